// Round 7
// baseline (1300.160 us; speedup 1.0000x reference)
//
#include <hip/hip_runtime.h>
#include <stdint.h>

typedef float f32x4 __attribute__((ext_vector_type(4)));
typedef int   i32x8 __attribute__((ext_vector_type(8)));
typedef long  i64x2 __attribute__((ext_vector_type(2)));

#define FP8_MAX_V 448.0f

// Pack 4 floats -> 4 OCP e4m3fn bytes, RNE, after reference-matching clip.
__device__ __forceinline__ uint32_t pack4_fp8(float a, float b, float c, float d) {
    a = fminf(fmaxf(a, -FP8_MAX_V), FP8_MAX_V);
    b = fminf(fmaxf(b, -FP8_MAX_V), FP8_MAX_V);
    c = fminf(fmaxf(c, -FP8_MAX_V), FP8_MAX_V);
    d = fminf(fmaxf(d, -FP8_MAX_V), FP8_MAX_V);
    int v = 0;
    v = __builtin_amdgcn_cvt_pk_fp8_f32(a, b, v, false);  // bytes 0,1
    v = __builtin_amdgcn_cvt_pk_fp8_f32(c, d, v, true);   // bytes 2,3
    return (uint32_t)v;
}

__global__ void quant_fp8_kernel(const float* __restrict__ in,
                                 uint32_t* __restrict__ out,
                                 const float* __restrict__ scale_ptr,
                                 long long n4) {
    const float s = scale_ptr[0];
    long long i = (long long)blockIdx.x * blockDim.x + threadIdx.x;
    const long long stride = (long long)gridDim.x * blockDim.x;
    const float4* in4 = (const float4*)in;
    for (; i < n4; i += stride) {
        float4 v = in4[i];
        out[i] = pack4_fp8(v.x / s, v.y / s, v.z / s, v.w / s);
    }
}

// MX-scaled fp8 GEMM. Round-6 kernel with the occupancy cap fixed: 48 KiB LDS
// and 120 VGPR allow 3 blocks/CU (144 KiB LDS, 12 waves/CU -> <=170 VGPR);
// round 6 mistakenly declared (256,2). Cross-block TLP is the only mechanism
// hiding the per-K-tile vmcnt(0) drain in this single-buffered loop.
// BM=256, BN=128, BK=128 B, 4 waves (2M x 2N), per-wave 128x64 out,
// 24 b128 reads / 32 MFMA per wave-K-tile. mfma_scale_f32_16x16x128_f8f6f4
// with E8M0 scales = 127 (1.0) == plain fp8 numerics.
// LDS swizzle: 16B slot = chunk ^ (row&7), on global SOURCE + ds_read addr.
__global__ __launch_bounds__(256, 3) void gemm_mxfp8_kernel(
    const uint8_t* __restrict__ qA,   // [M][K] fp8
    const uint8_t* __restrict__ qB,   // [N][K] fp8
    const float* __restrict__ bias,   // [N]
    const float* __restrict__ s_in_p,
    const float* __restrict__ s_w_p,
    float* __restrict__ C,            // [M][N] fp32
    int M, int N, int K) {
    __shared__ uint8_t lds[49152];    // A [256][128] + B [128][128]

    const int tid = threadIdx.x;
    const int w   = tid >> 6;   // wave 0..3
    const int l   = tid & 63;
    const int wr  = w >> 1;     // A rows [wr*128, +128)
    const int wc  = w & 1;      // B rows [wc*64, +64)
    const int lr  = l & 15;     // fragment row
    const int lg  = l >> 4;     // k-group: k in [lg*32, +32)
    const int lsw = lr & 7;     // XOR swizzle key

    // XCD-bijective block swizzle: grid = 1792 = 8 * 224.
    const int cpx = (int)gridDim.x >> 3;
    const int swz = ((int)blockIdx.x & 7) * cpx + ((int)blockIdx.x >> 3);
    const int bm  = (swz & 15) << 8;   // M/256 = 16 tiles
    const int bn  = (swz >> 4) << 7;   // N/128 = 112 tiles

    const float outscale = s_in_p[0] * s_w_p[0];
    const int NT = K >> 7;             // 32 K-tiles of 128 bytes

    // Two b128 reads per 32-B fragment: slots (2lg)^lsw and (2lg+1)^lsw.
    const int off0 = (((lg << 1) ^ lsw) << 4);
    const int off1 = off0 ^ 16;

    f32x4 acc[8][4];
#pragma unroll
    for (int mi = 0; mi < 8; ++mi)
#pragma unroll
        for (int ni = 0; ni < 4; ++ni)
            acc[mi][ni] = (f32x4){0.f, 0.f, 0.f, 0.f};

    // Staging: thread t covers row = t>>3, 16-B chunk t&7, source chunk
    // pre-swizzled with (row&7); later issues shift rows by 32 (mod-8 inv).
    const int srow = tid >> 3;
    const int sc   = (((tid & 7) ^ (srow & 7)) << 4);
    const uint8_t* sA = qA + (size_t)(bm + srow) * K + sc;
    const uint8_t* sB = qB + (size_t)(bn + srow) * K + sc;
    const int dstw = w << 10;   // wave-uniform LDS piece; HW adds lane*16

    union frag { i32x8 v; i64x2 h[2]; };

    for (int kt = 0; kt < NT; ++kt) {
        const int kb = kt << 7;
        // A tile: 256 rows = 8 issues of 32 rows (4 KiB each)
#pragma unroll
        for (int i = 0; i < 8; ++i) {
            __builtin_amdgcn_global_load_lds(
                (const __attribute__((address_space(1))) void*)(sA + (size_t)(i * 32) * K + kb),
                (__attribute__((address_space(3))) void*)(lds + i * 4096 + dstw), 16, 0, 0);
        }
        // B tile: 128 rows = 4 issues
#pragma unroll
        for (int i = 0; i < 4; ++i) {
            __builtin_amdgcn_global_load_lds(
                (const __attribute__((address_space(1))) void*)(sB + (size_t)(i * 32) * K + kb),
                (__attribute__((address_space(3))) void*)(lds + 32768 + i * 4096 + dstw), 16, 0, 0);
        }
        __syncthreads();

        i32x8 a[8];
#pragma unroll
        for (int mi = 0; mi < 8; ++mi) {
            const uint8_t* base = lds + ((wr * 128 + mi * 16 + lr) << 7);
            frag u;
            u.h[0] = *(const i64x2*)(base + off0);
            u.h[1] = *(const i64x2*)(base + off1);
            a[mi] = u.v;
        }
#pragma unroll
        for (int ni = 0; ni < 4; ++ni) {
            const uint8_t* base = lds + 32768 + ((wc * 64 + ni * 16 + lr) << 7);
            frag u;
            u.h[0] = *(const i64x2*)(base + off0);
            u.h[1] = *(const i64x2*)(base + off1);
            const i32x8 b = u.v;
#pragma unroll
            for (int mi = 0; mi < 8; ++mi)
                acc[mi][ni] = __builtin_amdgcn_mfma_scale_f32_16x16x128_f8f6f4(
                    a[mi], b, acc[mi][ni],
                    0, 0,          // cbsz=fp8(e4m3), blgp=fp8(e4m3)
                    0, 127,        // scale_a: E8M0 127 = 1.0
                    0, 127);       // scale_b: E8M0 127 = 1.0
        }
        // ds_reads must complete before next tile's stage overwrites.
        asm volatile("s_waitcnt lgkmcnt(0)" ::: "memory");
        __builtin_amdgcn_sched_barrier(0);
        __builtin_amdgcn_s_barrier();
    }

    // Epilogue. 16x16 C/D layout: col = lane&15, row = (lane>>4)*4 + reg.
    const int crow0 = bm + wr * 128 + (lg << 2);
    const int ccol0 = bn + wc * 64 + lr;
#pragma unroll
    for (int ni = 0; ni < 4; ++ni) {
        const int col = ccol0 + ni * 16;
        const float bv = bias[col];
#pragma unroll
        for (int mi = 0; mi < 8; ++mi) {
            const int row = crow0 + mi * 16;
#pragma unroll
            for (int r = 0; r < 4; ++r)
                C[(size_t)(row + r) * N + col] = acc[mi][ni][r] * outscale + bv;
        }
    }
}

extern "C" void kernel_launch(void* const* d_in, const int* in_sizes, int n_in,
                              void* d_out, int out_size, void* d_ws, size_t ws_size,
                              hipStream_t stream) {
    const float* x    = (const float*)d_in[0];
    const float* wt   = (const float*)d_in[1];
    const float* bias = (const float*)d_in[2];
    const float* s_in = (const float*)d_in[3];
    const float* s_w  = (const float*)d_in[4];
    float* out = (float*)d_out;

    const long long xe = in_sizes[0];            // M*K
    const long long we = in_sizes[1];            // N*K
    const int N = in_sizes[2];
    const int K = (int)(we / N);
    const int M = (int)(xe / K);

    uint8_t* qx = (uint8_t*)d_ws;                // M*K fp8
    uint8_t* qw = qx + xe;                       // N*K fp8

    quant_fp8_kernel<<<2048, 256, 0, stream>>>(x,  (uint32_t*)qx, s_in, xe >> 2);
    quant_fp8_kernel<<<2048, 256, 0, stream>>>(wt, (uint32_t*)qw, s_w,  we >> 2);

    dim3 grid((M / 256) * (N / 128));            // 16*112 = 1792 (8 | 1792)
    gemm_mxfp8_kernel<<<grid, 256, 0, stream>>>(qx, qw, bias, s_in, s_w, out,
                                                M, N, K);
}

// Round 8
// 398.697 us; speedup vs baseline: 3.2610x; 3.2610x over previous
//
#include <hip/hip_runtime.h>
#include <stdint.h>

typedef float f32x4 __attribute__((ext_vector_type(4)));
typedef int   i32x8 __attribute__((ext_vector_type(8)));
typedef long  i64x2 __attribute__((ext_vector_type(2)));

#define FP8_MAX_V 448.0f

// Pack 4 floats -> 4 OCP e4m3fn bytes, RNE, after reference-matching clip.
__device__ __forceinline__ uint32_t pack4_fp8(float a, float b, float c, float d) {
    a = fminf(fmaxf(a, -FP8_MAX_V), FP8_MAX_V);
    b = fminf(fmaxf(b, -FP8_MAX_V), FP8_MAX_V);
    c = fminf(fmaxf(c, -FP8_MAX_V), FP8_MAX_V);
    d = fminf(fmaxf(d, -FP8_MAX_V), FP8_MAX_V);
    int v = 0;
    v = __builtin_amdgcn_cvt_pk_fp8_f32(a, b, v, false);  // bytes 0,1
    v = __builtin_amdgcn_cvt_pk_fp8_f32(c, d, v, true);   // bytes 2,3
    return (uint32_t)v;
}

__global__ void quant_fp8_kernel(const float* __restrict__ in,
                                 uint32_t* __restrict__ out,
                                 const float* __restrict__ scale_ptr,
                                 long long n4) {
    const float s = scale_ptr[0];
    long long i = (long long)blockIdx.x * blockDim.x + threadIdx.x;
    const long long stride = (long long)gridDim.x * blockDim.x;
    const float4* in4 = (const float4*)in;
    for (; i < n4; i += stride) {
        float4 v = in4[i];
        out[i] = pack4_fp8(v.x / s, v.y / s, v.z / s, v.w / s);
    }
}

// MX-scaled fp8 GEMM — phase-pipelined (r3's proven-efficient schedule
// skeleton, whose MFMA-busy hit 88% of its floor) x r4's MX K=128 MFMA
// (whose floor is 2.3x cheaper). C = (qA . qB^T) * outscale + bias.
// BM=256, BN=128, BK=128 B. 512 threads / 8 waves (4M x 2N), per-wave 64x64
// out (acc 64 f32 -> no spill). LDS ring-3 x 48 KiB slots (A 32K + B 16K) =
// 144 KiB, 1 block/CU, prefetch distance 2. Per K-tile, 2 phases:
//   {stage 3 issues of T+2 ; ds_read frags ; s_barrier ; lgkmcnt(0) ;
//    setprio(1) ; 8 MFMA ; setprio(0) ; s_barrier}
// and ONE counted s_waitcnt vmcnt(6) at tile end (T+2's 6 issues stay in
// flight; T+1's, issued a full tile ago, are landed). Never vmcnt(0) in loop.
// LDS swizzle: 16B slot = chunk ^ (row&7) on global SOURCE + ds_read addr.
__global__ __launch_bounds__(512, 2) void gemm_mxfp8_kernel(
    const uint8_t* __restrict__ qA,   // [M][K] fp8
    const uint8_t* __restrict__ qB,   // [N][K] fp8
    const float* __restrict__ bias,   // [N]
    const float* __restrict__ s_in_p,
    const float* __restrict__ s_w_p,
    float* __restrict__ C,            // [M][N] fp32
    int M, int N, int K) {
    extern __shared__ uint8_t lds[];  // 3 * 49152 = 147456 B

    const int tid = threadIdx.x;
    const int w   = tid >> 6;   // wave 0..7
    const int l   = tid & 63;
    const int wr  = w >> 1;     // 0..3 -> A rows [wr*64, +64)
    const int wc  = w & 1;      // 0..1 -> B rows [wc*64, +64)
    const int lr  = l & 15;     // fragment row
    const int lg  = l >> 4;     // k-group: k in [lg*32, +32)
    const int lsw = lr & 7;     // XOR swizzle key

    // XCD-bijective block swizzle: grid = 1792 = 8 * 224 = 7 * 256.
    const int cpx = (int)gridDim.x >> 3;
    const int swz = ((int)blockIdx.x & 7) * cpx + ((int)blockIdx.x >> 3);
    const int bm  = (swz & 15) << 8;   // M/256 = 16 tiles
    const int bn  = (swz >> 4) << 7;   // N/128 = 112 tiles

    const float outscale = s_in_p[0] * s_w_p[0];
    const int NT = K >> 7;             // 32 K-tiles of 128 bytes

    // Two b128 reads per 32-B fragment: slots (2lg)^lsw and (2lg+1)^lsw.
    const int off0 = (((lg << 1) ^ lsw) << 4);
    const int off1 = off0 ^ 16;

    f32x4 acc[4][4];
#pragma unroll
    for (int mi = 0; mi < 4; ++mi)
#pragma unroll
        for (int ni = 0; ni < 4; ++ni)
            acc[mi][ni] = (f32x4){0.f, 0.f, 0.f, 0.f};

    // Staging: 512 threads x 16 B = 8 KiB = 64 rows/issue. A: 4 issues,
    // B: 2 issues (6/thread/tile). Source chunk pre-swizzled with (row&7);
    // issues shift rows by 64 -> invariant.
    const int srow = tid >> 3;                       // 0..63
    const int sc   = (((tid & 7) ^ (srow & 7)) << 4);
    const uint8_t* sA = qA + (size_t)(bm + srow) * K + sc;
    const uint8_t* sB = qB + (size_t)(bn + srow) * K + sc;
    const int dstw = w << 10;   // wave-uniform LDS piece; HW adds lane*16

#define STA(SL, I, KB) \
    __builtin_amdgcn_global_load_lds( \
        (const __attribute__((address_space(1))) void*)(sA + (size_t)((I) * 64) * K + (KB)), \
        (__attribute__((address_space(3))) void*)(lds + (SL) * 49152 + (I) * 8192 + dstw), 16, 0, 0)
#define STB(SL, I, KB) \
    __builtin_amdgcn_global_load_lds( \
        (const __attribute__((address_space(1))) void*)(sB + (size_t)((I) * 64) * K + (KB)), \
        (__attribute__((address_space(3))) void*)(lds + (SL) * 49152 + 32768 + (I) * 8192 + dstw), 16, 0, 0)

    union frag { i32x8 v; i64x2 h[2]; };

    // Prologue: stage tiles 0 and 1 (6 issues each); wait tile 0 landed.
    STA(0, 0, 0);  STA(0, 1, 0);  STA(0, 2, 0);  STA(0, 3, 0);
    STB(0, 0, 0);  STB(0, 1, 0);
    STA(1, 0, 128); STA(1, 1, 128); STA(1, 2, 128); STA(1, 3, 128);
    STB(1, 0, 128); STB(1, 1, 128);
    asm volatile("s_waitcnt vmcnt(6)" ::: "memory");
    __builtin_amdgcn_s_barrier();

    int s = 0;                         // T % 3
    for (int T = 0; T < NT; ++T) {
        const uint8_t* base = lds + s * 49152;
        int sp = s + 2; if (sp >= 3) sp -= 3;          // (T+2) % 3
        const int kbp = (T + 2 < NT ? T + 2 : 0) << 7; // clamp -> dead slot

        i32x8 a[4], b[2];
        // ---------------- phase 0: A frags + B0,B1 ; MFMA ni=0,1 ----------
        STA(sp, 0, kbp); STA(sp, 1, kbp); STA(sp, 2, kbp);
#pragma unroll
        for (int mi = 0; mi < 4; ++mi) {
            const uint8_t* p = base + ((wr * 64 + mi * 16 + lr) << 7);
            frag u;
            u.h[0] = *(const i64x2*)(p + off0);
            u.h[1] = *(const i64x2*)(p + off1);
            a[mi] = u.v;
        }
#pragma unroll
        for (int ni = 0; ni < 2; ++ni) {
            const uint8_t* p = base + 32768 + ((wc * 64 + ni * 16 + lr) << 7);
            frag u;
            u.h[0] = *(const i64x2*)(p + off0);
            u.h[1] = *(const i64x2*)(p + off1);
            b[ni] = u.v;
        }
        __builtin_amdgcn_s_barrier();
        asm volatile("s_waitcnt lgkmcnt(0)" ::: "memory");
        __builtin_amdgcn_sched_barrier(0);
        __builtin_amdgcn_s_setprio(1);
#pragma unroll
        for (int mi = 0; mi < 4; ++mi)
#pragma unroll
            for (int ni = 0; ni < 2; ++ni)
                acc[mi][ni] = __builtin_amdgcn_mfma_scale_f32_16x16x128_f8f6f4(
                    a[mi], b[ni], acc[mi][ni], 0, 0, 0, 127, 0, 127);
        __builtin_amdgcn_s_setprio(0);
        __builtin_amdgcn_s_barrier();

        // ---------------- phase 1: B2,B3 ; MFMA ni=2,3 --------------------
        STA(sp, 3, kbp); STB(sp, 0, kbp); STB(sp, 1, kbp);
#pragma unroll
        for (int ni = 0; ni < 2; ++ni) {
            const uint8_t* p = base + 32768 + ((wc * 64 + (ni + 2) * 16 + lr) << 7);
            frag u;
            u.h[0] = *(const i64x2*)(p + off0);
            u.h[1] = *(const i64x2*)(p + off1);
            b[ni] = u.v;
        }
        __builtin_amdgcn_s_barrier();
        asm volatile("s_waitcnt lgkmcnt(0)" ::: "memory");
        __builtin_amdgcn_sched_barrier(0);
        __builtin_amdgcn_s_setprio(1);
#pragma unroll
        for (int mi = 0; mi < 4; ++mi)
#pragma unroll
            for (int ni = 0; ni < 2; ++ni)
                acc[mi][ni + 2] = __builtin_amdgcn_mfma_scale_f32_16x16x128_f8f6f4(
                    a[mi], b[ni], acc[mi][ni + 2], 0, 0, 0, 127, 0, 127);
        __builtin_amdgcn_s_setprio(0);
        // T+1's 6 issues (a full tile old) land; T+2's 6 stay in flight.
        asm volatile("s_waitcnt vmcnt(6)" ::: "memory");
        __builtin_amdgcn_s_barrier();

        if (++s == 3) s = 0;
    }

    // Epilogue. 16x16 C/D layout: col = lane&15, row = (lane>>4)*4 + reg.
    const int crow0 = bm + wr * 64 + (lg << 2);
    const int ccol0 = bn + wc * 64 + lr;
#pragma unroll
    for (int ni = 0; ni < 4; ++ni) {
        const int col = ccol0 + ni * 16;
        const float bv = bias[col];
#pragma unroll
        for (int mi = 0; mi < 4; ++mi) {
            const int row = crow0 + mi * 16;
#pragma unroll
            for (int r = 0; r < 4; ++r)
                C[(size_t)(row + r) * N + col] = acc[mi][ni][r] * outscale + bv;
        }
    }
#undef STA
#undef STB
}

extern "C" void kernel_launch(void* const* d_in, const int* in_sizes, int n_in,
                              void* d_out, int out_size, void* d_ws, size_t ws_size,
                              hipStream_t stream) {
    const float* x    = (const float*)d_in[0];
    const float* wt   = (const float*)d_in[1];
    const float* bias = (const float*)d_in[2];
    const float* s_in = (const float*)d_in[3];
    const float* s_w  = (const float*)d_in[4];
    float* out = (float*)d_out;

    const long long xe = in_sizes[0];            // M*K
    const long long we = in_sizes[1];            // N*K
    const int N = in_sizes[2];
    const int K = (int)(we / N);
    const int M = (int)(xe / K);

    uint8_t* qx = (uint8_t*)d_ws;                // M*K fp8
    uint8_t* qw = qx + xe;                       // N*K fp8

    quant_fp8_kernel<<<2048, 256, 0, stream>>>(x,  (uint32_t*)qx, s_in, xe >> 2);
    quant_fp8_kernel<<<2048, 256, 0, stream>>>(wt, (uint32_t*)qw, s_w,  we >> 2);

    dim3 grid((M / 256) * (N / 128));            // 16*112 = 1792 = 7/CU exact
    gemm_mxfp8_kernel<<<grid, 512, 147456, stream>>>(qx, qw, bias, s_in, s_w,
                                                     out, M, N, K);
}